// Round 18
// baseline (283.257 us; speedup 1.0000x reference)
//
#include <hip/hip_runtime.h>
#include <hip/hip_bf16.h>
#include <math.h>

// B=128, T=512, D=512, K=64; mid=64; rows per half = 32768. f32 in/out.
typedef unsigned short u16;
typedef __attribute__((ext_vector_type(4))) float f32x4;
typedef __attribute__((ext_vector_type(8))) short s16x8;
typedef __attribute__((ext_vector_type(4))) short s16x4;

// ---------------- output offsets (f32 elements) ----------------
#define O_FM    0ULL
#define O_TRIP  67108864ULL
#define O_KL    67108865ULL
#define O_DIST  67108866ULL
#define O_AATT  67108867ULL
#define O_NATT  67141635ULL
#define O_ANATT 67174403ULL
#define O_NAATT 67207171ULL

// ---------------- ws offsets (bytes), total ~18.6 MB (ws_size ~1 GB) ----------------
#define WS_ATTB  0ULL          // att bf16 [65536][128]
#define WS_BCT   16777216ULL   // bf16 [512 n][128 k]: k<64 = pam^T, k>=64 = pnm^T
#define WS_PVT   16908288ULL   // bf16 [512 n][64 k] = pnv^T
#define WS_PAM   16973824ULL   // f32 [64][512]
#define WS_PNM   17104896ULL   // f32 [64][512]
#define WS_PNV   17235968ULL   // f32 [64][512]
#define WS_MBH   17367040ULL   // bf16 [128 k][512 d] mem hi
#define WS_MBL   17498112ULL   // bf16 [128 k][512 d] mem lo
#define WS_TATT  17629184ULL   // f32 [3][32768]
#define WS_IDX   18022400ULL   // int [3][64][40]
#define WS_GATH  18053120ULL   // f32 [3][64][512]
#define WS_NORM  18446336ULL   // f32 [128]
#define WS_KL    18446848ULL   // f32
#define WS_TRIPB 18447360ULL   // f32 [64]
#define WS_SUM   18447616ULL   // f32 [64][512]

__device__ __forceinline__ u16 f2bf(float f) {
    union { float f; unsigned int u; } c; c.f = f;
    unsigned int r = c.u + 0x7fffu + ((c.u >> 16) & 1u);
    return (u16)(r >> 16);
}
__device__ __forceinline__ float bf2f(u16 h) {
    union { unsigned int u; float f; } c; c.u = ((unsigned int)h) << 16;
    return c.f;
}

__device__ __forceinline__ float blk_sum(float v, float* red) {
    #pragma unroll
    for (int o = 32; o; o >>= 1) v += __shfl_xor(v, o);
    int tid = threadIdx.x;
    if ((tid & 63) == 0) red[tid >> 6] = v;
    __syncthreads();
    float r = red[0] + red[1] + red[2] + red[3];
    __syncthreads();
    return r;
}

// 512-thread block sum; waves 4-7 padded with zeros -> bit-identical to 4-wave version
__device__ __forceinline__ float blk_sum8(float v, float* red, int tid) {
    #pragma unroll
    for (int o = 32; o; o >>= 1) v += __shfl_xor(v, o);
    if ((tid & 63) == 0) red[tid >> 6] = v;
    __syncthreads();
    float r = red[0];
    #pragma unroll
    for (int i = 1; i < 8; ++i) r += red[i];
    __syncthreads();
    return r;
}

// stage a 128x32 bf16 tile into LDS linearly (512 threads, one 16B load each)
__device__ __forceinline__ void stage32_512(const u16* __restrict__ g, int row0, int ld, int k0,
                                            u16* s, int tid) {
    const u16* src = g + (size_t)(row0 + (tid >> 2)) * ld + k0 + (tid & 3) * 8;
    __builtin_amdgcn_global_load_lds((const __attribute__((address_space(1))) void*)src,
                                     (__attribute__((address_space(3))) void*)(s + tid * 8),
                                     16, 0, 0);
}

// ---------------- k_pp: prep (256 blocks) + proj (192 blocks) ----------------
__global__ __launch_bounds__(256) void k_pp(const float* __restrict__ Amem, const float* __restrict__ Nmem,
                                            const float* __restrict__ Wmu, const float* __restrict__ Wvar,
                                            char* __restrict__ ws) {
    __shared__ float mr[512];
    int bid = blockIdx.x, tid = threadIdx.x;
    if (bid < 256) {
        int i = bid * 256 + tid;
        if (i == 0) *(float*)(ws + WS_KL) = 0.f;
        if (i < 32768) ((float*)(ws + WS_SUM))[i] = 0.f;
        int k = i >> 9, d = i & 511;
        float v = (k < 64) ? Amem[(size_t)k * 512 + d] : Nmem[(size_t)(k - 64) * 512 + d];
        u16 h = f2bf(v);
        ((u16*)(ws + WS_MBH))[i] = h;
        ((u16*)(ws + WS_MBL))[i] = f2bf(v - bf2f(h));
        return;
    }
    int pb = bid - 256;
    float* pam = (float*)(ws + WS_PAM);
    float* pnm = (float*)(ws + WS_PNM);
    float* pnv = (float*)(ws + WS_PNV);
    u16* bct = (u16*)(ws + WS_BCT);
    u16* pvt = (u16*)(ws + WS_PVT);
    int mat = pb >> 6, k = pb & 63;
    const float* mrow = ((mat == 0) ? Amem : Nmem) + (size_t)k * 512;
    const float* W = (mat == 2) ? Wvar : Wmu;
    mr[tid] = mrow[tid]; mr[tid + 256] = mrow[tid + 256];
    __syncthreads();
    float s0 = 0.f, s1 = 0.f;
    for (int d = 0; d < 512; ++d) {
        float m = mr[d];
        s0 += m * W[(size_t)d * 512 + tid];
        s1 += m * W[(size_t)d * 512 + tid + 256];
    }
    if (mat == 0) {
        pam[(size_t)k * 512 + tid] = s0; pam[(size_t)k * 512 + tid + 256] = s1;
        bct[(size_t)tid * 128 + k] = f2bf(s0); bct[(size_t)(tid + 256) * 128 + k] = f2bf(s1);
    } else if (mat == 1) {
        pnm[(size_t)k * 512 + tid] = s0; pnm[(size_t)k * 512 + tid + 256] = s1;
        bct[(size_t)tid * 128 + 64 + k] = f2bf(s0); bct[(size_t)(tid + 256) * 128 + 64 + k] = f2bf(s1);
    } else {
        pnv[(size_t)k * 512 + tid] = s0; pnv[(size_t)k * 512 + tid + 256] = s1;
        pvt[(size_t)tid * 64 + k] = f2bf(s0); pvt[(size_t)(tid + 256) * 64 + k] = f2bf(s1);
    }
}

// ---------------- dots via split-bf16 MFMA: 1024 blocks x 64 rows, 2x4 wave split ----------
// wave wid: rows (wid&3)*16..+15, cols (wid>>2)*64..+63. acc order per element unchanged
// (dc ascending; hh, hl, lh) -> bit-identical att vs round-13/17 versions.
__global__ __launch_bounds__(512) void k_dots(const float* __restrict__ x, char* __restrict__ ws,
                                              float* __restrict__ out) {
    __shared__ u16 sXh[64 * 32];
    __shared__ u16 sXl[64 * 32];
    __shared__ u16 sBh[128 * 32];
    __shared__ u16 sBl[128 * 32];

    int tid = threadIdx.x;
    int row0 = blockIdx.x * 64;
    const u16* mbh = (const u16*)(ws + WS_MBH);
    const u16* mbl = (const u16*)(ws + WS_MBL);
    u16* attb = (u16*)(ws + WS_ATTB);
    int lane = tid & 63, wid = tid >> 6;
    int cl = lane & 15, rq = lane >> 4;
    int wr4 = wid & 3, side = wid >> 2;

    f32x4 acc[4];
    #pragma unroll
    for (int i = 0; i < 4; ++i) acc[i] = (f32x4)0.f;

    for (int dc = 0; dc < 16; ++dc) {
        int d0 = dc * 32;
        {   // stage x chunk [64 rows][32 d]: F_M copy + hi/lo bf16 into LDS (one f32x4/thread)
            int r = tid >> 3, cg = tid & 7;
            const float* sp = x + (size_t)(row0 + r) * 512 + d0 + cg * 4;
            float* op = out + (size_t)(row0 + r) * 1024 + d0 + cg * 4;
            f32x4 v = *(const f32x4*)sp;
            *(f32x4*)op = v;
            s16x4 hs, ls;
            #pragma unroll
            for (int j = 0; j < 4; ++j) {
                u16 h = f2bf(v[j]);
                hs[j] = (short)h;
                ls[j] = (short)f2bf(v[j] - bf2f(h));
            }
            *(s16x4*)&sXh[r * 32 + cg * 4] = hs;
            *(s16x4*)&sXl[r * 32 + cg * 4] = ls;
        }
        stage32_512(mbh, 0, 512, d0, sBh, tid);
        stage32_512(mbl, 0, 512, d0, sBl, tid);
        __syncthreads();
        s16x8 axh = *(const s16x8*)&sXh[(wr4 * 16 + cl) * 32 + rq * 8];
        s16x8 axl = *(const s16x8*)&sXl[(wr4 * 16 + cl) * 32 + rq * 8];
        #pragma unroll
        for (int ni = 0; ni < 4; ++ni) {
            s16x8 bh = *(const s16x8*)&sBh[(side * 64 + ni * 16 + cl) * 32 + rq * 8];
            s16x8 bl = *(const s16x8*)&sBl[(side * 64 + ni * 16 + cl) * 32 + rq * 8];
            acc[ni] = __builtin_amdgcn_mfma_f32_16x16x32_bf16(axh, bh, acc[ni], 0, 0, 0);
            acc[ni] = __builtin_amdgcn_mfma_f32_16x16x32_bf16(axh, bl, acc[ni], 0, 0, 0);
            acc[ni] = __builtin_amdgcn_mfma_f32_16x16x32_bf16(axl, bh, acc[ni], 0, 0, 0);
        }
        __syncthreads();
    }

    // sigmoid + attb write; acc[ni][q] -> row = row0 + wr4*16 + rq*4 + q, col = side*64 + ni*16 + cl
    #pragma unroll
    for (int ni = 0; ni < 4; ++ni) {
        #pragma unroll
        for (int q = 0; q < 4; ++q) {
            float logit = acc[ni][q] * 0.044194173824159216f;  // 1/sqrt(512)
            float av = 1.f / (1.f + expf(-logit));
            acc[ni][q] = av;
            attb[(size_t)(row0 + wr4 * 16 + rq * 4 + q) * 128 + side * 64 + ni * 16 + cl] = f2bf(av);
        }
    }

    // t_att: top-5-of-64 per (row, side); 16-lane (rq) group holds all 64 cols of this side
    unsigned long long gmask = 0xFFFFull << (lane & 48);
    float* tatt = (float*)(ws + WS_TATT);
    int half = row0 >> 15;
    #pragma unroll
    for (int q = 0; q < 4; ++q) {
        float v0 = acc[0][q], v1 = acc[1][q], v2 = acc[2][q], v3 = acc[3][q];
        float sum5 = 0.f;
        #pragma unroll
        for (int it = 0; it < 5; ++it) {
            float m = v0; int jm = 0;
            if (v1 > m) { m = v1; jm = 1; }
            if (v2 > m) { m = v2; jm = 2; }
            if (v3 > m) { m = v3; jm = 3; }
            float g = m;
            g = fmaxf(g, __shfl_xor(g, 1));
            g = fmaxf(g, __shfl_xor(g, 2));
            g = fmaxf(g, __shfl_xor(g, 4));
            g = fmaxf(g, __shfl_xor(g, 8));
            sum5 += g;
            unsigned long long bl = __ballot(m == g) & gmask;
            int owner = __ffsll(bl) - 1;
            if (lane == owner) {
                if (jm == 0) v0 = -INFINITY;
                else if (jm == 1) v1 = -INFINITY;
                else if (jm == 2) v2 = -INFINITY;
                else v3 = -INFINITY;
            }
        }
        if (cl == 0) {
            float tv = sum5 / 5.f;
            int lr = (row0 + wr4 * 16 + rq * 4 + q) & 32767;
            if (half) {
                if (side == 0) { out[O_AATT + lr]  = tv; tatt[lr] = tv; }
                else           { out[O_NAATT + lr] = tv; tatt[2 * 32768 + lr] = tv; }
            } else {
                if (side == 0) { out[O_ANATT + lr] = tv; }
                else           { out[O_NATT + lr]  = tv; tatt[32768 + lr] = tv; }
            }
        }
    }
}

// ---------------- bodies ----------------
__device__ __forceinline__ void body_G1(char* smem, int m0, int c0, int tid,
                                        const u16* __restrict__ attb, const u16* __restrict__ bct,
                                        const u16* __restrict__ pvt, const float* __restrict__ bmu,
                                        const float* __restrict__ bvar, const float* __restrict__ epsv,
                                        float* __restrict__ fm, float* __restrict__ klacc) {
    u16* sAA = (u16*)(smem);
    u16* sAN = (u16*)(smem + 8192);
    u16* sBA = (u16*)(smem + 16384);
    u16* sBN = (u16*)(smem + 24576);
    u16* sBV = (u16*)(smem + 32768);
    float* red = (float*)(smem + 40960);
    int lane = tid & 63, wid = tid >> 6;
    int wr = wid >> 2, wc = wid & 3;
    int cl = lane & 15, rq = lane >> 4;

    f32x4 aA[4][2], aN[4][2], aV[4][2];
    #pragma unroll
    for (int i = 0; i < 4; ++i)
        #pragma unroll
        for (int j = 0; j < 2; ++j) { aA[i][j] = (f32x4)0.f; aN[i][j] = (f32x4)0.f; aV[i][j] = (f32x4)0.f; }

    for (int kt = 0; kt < 2; ++kt) {
        stage32_512(attb, m0, 128, kt * 32, sAA, tid);
        stage32_512(attb, m0, 128, 64 + kt * 32, sAN, tid);
        stage32_512(bct, c0, 128, kt * 32, sBA, tid);
        stage32_512(bct, c0, 128, 64 + kt * 32, sBN, tid);
        stage32_512(pvt, c0, 64, kt * 32, sBV, tid);
        __syncthreads();
        s16x8 fA[4], fN[4], bA[2], bN[2], bV[2];
        #pragma unroll
        for (int i = 0; i < 4; ++i) {
            fA[i] = *(const s16x8*)&sAA[(wr * 64 + i * 16 + cl) * 32 + rq * 8];
            fN[i] = *(const s16x8*)&sAN[(wr * 64 + i * 16 + cl) * 32 + rq * 8];
        }
        #pragma unroll
        for (int n = 0; n < 2; ++n) {
            bA[n] = *(const s16x8*)&sBA[(wc * 32 + n * 16 + cl) * 32 + rq * 8];
            bN[n] = *(const s16x8*)&sBN[(wc * 32 + n * 16 + cl) * 32 + rq * 8];
            bV[n] = *(const s16x8*)&sBV[(wc * 32 + n * 16 + cl) * 32 + rq * 8];
        }
        #pragma unroll
        for (int mi = 0; mi < 4; ++mi)
            #pragma unroll
            for (int ni = 0; ni < 2; ++ni) {
                aA[mi][ni] = __builtin_amdgcn_mfma_f32_16x16x32_bf16(fA[mi], bA[ni], aA[mi][ni], 0, 0, 0);
                aN[mi][ni] = __builtin_amdgcn_mfma_f32_16x16x32_bf16(fN[mi], bN[ni], aN[mi][ni], 0, 0, 0);
                aV[mi][ni] = __builtin_amdgcn_mfma_f32_16x16x32_bf16(fN[mi], bV[ni], aV[mi][ni], 0, 0, 0);
            }
        __syncthreads();
    }

    float kll = 0.f;
    #pragma unroll
    for (int mi = 0; mi < 4; ++mi)
        #pragma unroll
        for (int ni = 0; ni < 2; ++ni) {
            int col = c0 + wc * 32 + ni * 16 + cl;
            int rowb = m0 + wr * 64 + mi * 16 + rq * 4;
            float bm = bmu[col], bv = bvar[col];
            #pragma unroll
            for (int q = 0; q < 4; ++q) {
                int row = rowb + q;
                float muN = aN[mi][ni][q] + bm;
                float var = aV[mi][ni][q] + bv;
                float ev = expf(var);
                float muA = aA[mi][ni][q] + bm;
                fm[(size_t)row * 1024 + 512 + col] =
                    muN + epsv[(size_t)row * 512 + col] * sqrtf(ev) + muA;
                kll += 1.f + var - muN * muN - ev;
            }
        }
    #pragma unroll
    for (int o = 32; o; o >>= 1) kll += __shfl_xor(kll, o);
    if (lane == 0) red[wid] = kll;
    __syncthreads();
    if (tid == 0) {
        float s = 0.f;
        #pragma unroll
        for (int i = 0; i < 8; ++i) s += red[i];
        atomicAdd(klacc, s);
    }
}

__device__ __forceinline__ void body_G3(char* smem, int m0, int c0, int tid,
                                        const u16* __restrict__ attb, const u16* __restrict__ bct,
                                        const float* __restrict__ bmu, float* __restrict__ fm) {
    u16* sA = (u16*)(smem);
    u16* sB = (u16*)(smem + 8192);
    int lane = tid & 63, wid = tid >> 6;
    int wr = wid >> 2, wc = wid & 3;
    int cl = lane & 15, rq = lane >> 4;

    f32x4 acc[4][2];
    #pragma unroll
    for (int i = 0; i < 4; ++i)
        #pragma unroll
        for (int j = 0; j < 2; ++j) acc[i][j] = (f32x4)0.f;

    for (int kt = 0; kt < 4; ++kt) {
        stage32_512(attb, 32768 + m0, 128, kt * 32, sA, tid);
        stage32_512(bct, c0, 128, kt * 32, sB, tid);
        __syncthreads();
        s16x8 fa[4], fb[2];
        #pragma unroll
        for (int i = 0; i < 4; ++i)
            fa[i] = *(const s16x8*)&sA[(wr * 64 + i * 16 + cl) * 32 + rq * 8];
        #pragma unroll
        for (int n = 0; n < 2; ++n)
            fb[n] = *(const s16x8*)&sB[(wc * 32 + n * 16 + cl) * 32 + rq * 8];
        #pragma unroll
        for (int mi = 0; mi < 4; ++mi)
            #pragma unroll
            for (int ni = 0; ni < 2; ++ni)
                acc[mi][ni] = __builtin_amdgcn_mfma_f32_16x16x32_bf16(fa[mi], fb[ni], acc[mi][ni], 0, 0, 0);
        __syncthreads();
    }
    #pragma unroll
    for (int mi = 0; mi < 4; ++mi)
        #pragma unroll
        for (int ni = 0; ni < 2; ++ni) {
            int col = c0 + wc * 32 + ni * 16 + cl;
            int rowb = 32768 + m0 + wr * 64 + mi * 16 + rq * 4;
            float bm2 = 2.f * bmu[col];
            #pragma unroll
            for (int q = 0; q < 4; ++q)
                fm[(size_t)(rowb + q) * 1024 + 512 + col] = acc[mi][ni][q] + bm2;
        }
}

// tg body for 512-thread block: tid<256 guards, wave-uniform barriers; math identical
__device__ __forceinline__ void body_tg(char* smem, int sb, int tid,
                                        const float* __restrict__ tatt, int* __restrict__ idx,
                                        const float* __restrict__ x, float* __restrict__ gath) {
    float* vals = (float*)smem;
    int* il = (int*)(smem + 2048);
    int s = sb >> 6, b = sb & 63;
    const float* src = tatt + (size_t)s * 32768 + b * 512;
    if (tid < 256) { vals[tid] = src[tid]; vals[tid + 256] = src[tid + 256]; }
    __syncthreads();
    if (tid < 256) {
        #pragma unroll
        for (int e = 0; e < 2; ++e) {
            int i = tid + e * 256;
            float v = vals[i];
            int rank = 0;
            for (int j = 0; j < 512; j += 4) {
                f32x4 w4 = *(const f32x4*)&vals[j];
                rank += (w4.x > v) || (w4.x == v && (j + 0) < i);
                rank += (w4.y > v) || (w4.y == v && (j + 1) < i);
                rank += (w4.z > v) || (w4.z == v && (j + 2) < i);
                rank += (w4.w > v) || (w4.w == v && (j + 3) < i);
            }
            if (rank < 33) { idx[(s * 64 + b) * 40 + rank] = i; il[rank] = i; }
        }
    }
    __syncthreads();
    if (tid < 256) {
        int srcb = (s == 1) ? b : 64 + b;
        const float* xb = x + (size_t)srcb * 262144;
        int d0 = tid * 2;
        float a0 = 0.f, a1 = 0.f;
        for (int i = 0; i < 33; ++i) {
            const float* p = xb + (size_t)il[i] * 512 + d0;
            a0 += p[0]; a1 += p[1];
        }
        gath[((size_t)s * 64 + b) * 512 + d0]     = a0 / 33.f;
        gath[((size_t)s * 64 + b) * 512 + d0 + 1] = a1 / 33.f;
    }
}

__device__ __forceinline__ void body_g2a(char* smem, int blk, int tid,
                                         const int* __restrict__ idx, const u16* __restrict__ attb,
                                         const float* __restrict__ pnm, const float* __restrict__ pnv,
                                         const float* __restrict__ bmu, const float* __restrict__ bvar,
                                         const float* __restrict__ epsv, float* __restrict__ SUM) {
    float* arow = (float*)smem;
    int b = blk / 3, seg = blk % 3;
    float s0 = 0.f, s1 = 0.f;
    for (int i = seg * 11; i < seg * 11 + 11; ++i) {
        int t = idx[(64 + b) * 40 + i];   // N_idx
        size_t r = (size_t)b * 512 + t;
        __syncthreads();
        if (tid < 64) arow[tid] = bf2f(attb[r * 128 + 64 + tid]);
        __syncthreads();
        if (tid < 256) {
            float mu0 = bmu[tid], mu1 = bmu[tid + 256];
            float v0 = bvar[tid], v1 = bvar[tid + 256];
            for (int k = 0; k < 64; ++k) {
                float a = arow[k];
                mu0 += a * pnm[(size_t)k * 512 + tid];
                mu1 += a * pnm[(size_t)k * 512 + tid + 256];
                v0  += a * pnv[(size_t)k * 512 + tid];
                v1  += a * pnv[(size_t)k * 512 + tid + 256];
            }
            s0 += mu0 + epsv[r * 512 + tid]       * sqrtf(expf(v0));
            s1 += mu1 + epsv[r * 512 + tid + 256] * sqrtf(expf(v1));
        }
    }
    if (tid < 256) {
        atomicAdd(&SUM[(size_t)b * 512 + tid], s0);
        atomicAdd(&SUM[(size_t)b * 512 + tid + 256], s1);
    }
}

__device__ __forceinline__ void body_g2b(char* smem, int b, int tid,
                                         const int* __restrict__ idx, const u16* __restrict__ attb,
                                         const float* __restrict__ pam, const float* __restrict__ bmu,
                                         float* __restrict__ norms) {
    float* meanA = (float*)smem;
    float* red = (float*)(smem + 256);
    if (tid < 64) {
        float s = 0.f;
        for (int i = 0; i < 33; ++i) {
            int t = idx[b * 40 + i];      // A_idx
            s += bf2f(attb[(size_t)(32768 + b * 512 + t) * 128 + tid]);
        }
        meanA[tid] = s * (1.f / 33.f);
    }
    __syncthreads();
    float ssv = 0.f;
    if (tid < 256) {
        float s0 = bmu[tid], s1 = bmu[tid + 256];
        #pragma unroll 4
        for (int k = 0; k < 64; ++k) {
            float m = meanA[k];
            s0 += m * pam[(size_t)k * 512 + tid];
            s1 += m * pam[(size_t)k * 512 + tid + 256];
        }
        ssv = s0 * s0 + s1 * s1;
    }
    float ss = blk_sum8(ssv, red, tid);
    if (tid == 0) norms[64 + b] = sqrtf(ss);
}

__device__ __forceinline__ void body_trip(char* smem, int b, int tid,
                                          const float* __restrict__ gath, float* __restrict__ tripb) {
    float* red = (float*)smem;
    const float* a = gath + (size_t)(64 + b) * 512;
    const float* p = gath + (size_t)(128 + b) * 512;
    const float* n = gath + (size_t)(b) * 512;
    float a0 = 0.f, a1 = 0.f, p0 = 0.f, p1 = 0.f, n0 = 0.f, n1 = 0.f;
    if (tid < 256) {
        a0 = a[tid]; a1 = a[tid + 256];
        p0 = p[tid]; p1 = p[tid + 256];
        n0 = n[tid]; n1 = n[tid + 256];
    }
    float na  = sqrtf(blk_sum8(tid < 256 ? a0 * a0 + a1 * a1 : 0.f, red, tid));
    float npv = sqrtf(blk_sum8(tid < 256 ? p0 * p0 + p1 * p1 : 0.f, red, tid));
    float nn  = sqrtf(blk_sum8(tid < 256 ? n0 * n0 + n1 * n1 : 0.f, red, tid));
    float e0 = 0.f, e1 = 0.f, f0 = 0.f, f1 = 0.f;
    if (tid < 256) {
        e0 = a0 / na - p0 / npv + 1e-6f; e1 = a1 / na - p1 / npv + 1e-6f;
        f0 = a0 / na - n0 / nn  + 1e-6f; f1 = a1 / na - n1 / nn  + 1e-6f;
    }
    float dap = sqrtf(blk_sum8(tid < 256 ? e0 * e0 + e1 * e1 : 0.f, red, tid));
    float dan = sqrtf(blk_sum8(tid < 256 ? f0 * f0 + f1 * f1 : 0.f, red, tid));
    if (tid == 0) tripb[b] = fmaxf(dap - dan + 1.f, 0.f);
}

// ---------------- k_postA: G1 (1024) + G3 (1024) + tg (192) ----------------
__global__ __launch_bounds__(512) void k_postA(const u16* __restrict__ attb, const u16* __restrict__ bct,
                                               const u16* __restrict__ pvt, const float* __restrict__ bmu,
                                               const float* __restrict__ bvar, const float* __restrict__ epsv,
                                               const float* __restrict__ tatt, int* __restrict__ idx,
                                               const float* __restrict__ x, float* __restrict__ gath,
                                               float* __restrict__ fm, float* __restrict__ klacc) {
    __shared__ __align__(16) char smem[41024];
    int bid = blockIdx.x, tid = threadIdx.x;
    if (bid < 1024) {
        body_G1(smem, (bid >> 2) * 128, (bid & 3) * 128, tid, attb, bct, pvt, bmu, bvar, epsv, fm, klacc);
    } else if (bid < 2048) {
        int b2 = bid - 1024;
        body_G3(smem, (b2 >> 2) * 128, (b2 & 3) * 128, tid, attb, bct, bmu, fm);
    } else {
        body_tg(smem, bid - 2048, tid, tatt, idx, x, gath);
    }
}

// ---------------- k_postB: g2a (192) + g2b (64) + trip (64) ----------------
__global__ __launch_bounds__(512) void k_postB(const int* __restrict__ idx, const u16* __restrict__ attb,
                                               const float* __restrict__ pam, const float* __restrict__ pnm,
                                               const float* __restrict__ pnv, const float* __restrict__ bmu,
                                               const float* __restrict__ bvar, const float* __restrict__ epsv,
                                               const float* __restrict__ gath, float* __restrict__ SUM,
                                               float* __restrict__ norms, float* __restrict__ tripb) {
    __shared__ __align__(16) char smem[2304];
    int bid = blockIdx.x, tid = threadIdx.x;
    if (bid < 192) {
        body_g2a(smem, bid, tid, idx, attb, pnm, pnv, bmu, bvar, epsv, SUM);
    } else if (bid < 256) {
        body_g2b(smem, bid - 192, tid, idx, attb, pam, bmu, norms);
    } else {
        body_trip(smem, bid - 256, tid, gath, tripb);
    }
}

// ---------------- k_norm2a: anchor norms from SUM (64 blocks, 256 threads) ----------------
__global__ __launch_bounds__(256) void k_norm2a(const float* __restrict__ SUM, float* __restrict__ norms) {
    __shared__ float red[8];
    int b = blockIdx.x, tid = threadIdx.x;
    float s0 = SUM[(size_t)b * 512 + tid] / 33.f;
    float s1 = SUM[(size_t)b * 512 + tid + 256] / 33.f;
    float ss = blk_sum(s0 * s0 + s1 * s1, red);
    if (tid == 0) norms[b] = sqrtf(ss);
}

// ---------------- finalize: triplet + distance + kl ----------------
__global__ __launch_bounds__(64) void k_final(const float* __restrict__ norms, const float* __restrict__ klacc,
                                              const float* __restrict__ tripb, float* __restrict__ out) {
    int tid = threadIdx.x;
    float v = fmaxf(100.f - norms[64 + tid] + norms[tid], 0.f);
    float t = tripb[tid];
    #pragma unroll
    for (int o = 32; o; o >>= 1) { v += __shfl_xor(v, o); t += __shfl_xor(t, o); }
    if (tid == 0) {
        out[O_DIST] = v / 64.f;
        out[O_TRIP] = t / 64.f;
        out[O_KL]   = -0.5f * (*klacc) / 32768.f;
    }
}

extern "C" void kernel_launch(void* const* d_in, const int* in_sizes, int n_in,
                              void* d_out, int out_size, void* d_ws, size_t ws_size,
                              hipStream_t stream) {
    const float* x    = (const float*)d_in[0];
    const float* Amem = (const float*)d_in[1];
    const float* Nmem = (const float*)d_in[2];
    const float* Wmu  = (const float*)d_in[3];
    const float* bmu  = (const float*)d_in[4];
    const float* Wvar = (const float*)d_in[5];
    const float* bvar = (const float*)d_in[6];
    const float* eps  = (const float*)d_in[7];
    float* out = (float*)d_out;
    char* ws = (char*)d_ws;
    const u16* attb  = (const u16*)(ws + WS_ATTB);
    const u16* bct   = (const u16*)(ws + WS_BCT);
    const u16* pvt   = (const u16*)(ws + WS_PVT);
    const float* pam = (const float*)(ws + WS_PAM);
    const float* pnm = (const float*)(ws + WS_PNM);
    const float* pnv = (const float*)(ws + WS_PNV);
    const int* idx   = (const int*)(ws + WS_IDX);

    k_pp<<<448, 256, 0, stream>>>(Amem, Nmem, Wmu, Wvar, ws);
    k_dots<<<1024, 512, 0, stream>>>(x, ws, out);
    k_postA<<<2240, 512, 0, stream>>>(attb, bct, pvt, bmu, bvar, eps,
                                      (const float*)(ws + WS_TATT), (int*)(ws + WS_IDX), x,
                                      (float*)(ws + WS_GATH), out, (float*)(ws + WS_KL));
    k_postB<<<320, 512, 0, stream>>>(idx, attb, pam, pnm, pnv, bmu, bvar, eps,
                                     (const float*)(ws + WS_GATH), (float*)(ws + WS_SUM),
                                     (float*)(ws + WS_NORM), (float*)(ws + WS_TRIPB));
    k_norm2a<<<64, 256, 0, stream>>>((const float*)(ws + WS_SUM), (float*)(ws + WS_NORM));
    k_final<<<1, 64, 0, stream>>>((const float*)(ws + WS_NORM), (const float*)(ws + WS_KL),
                                  (const float*)(ws + WS_TRIPB), out);
}

// Round 19
// 272.299 us; speedup vs baseline: 1.0402x; 1.0402x over previous
//
#include <hip/hip_runtime.h>
#include <hip/hip_bf16.h>
#include <math.h>

// B=128, T=512, D=512, K=64; mid=64; rows per half = 32768. f32 in/out.
typedef unsigned short u16;
typedef __attribute__((ext_vector_type(4))) float f32x4;
typedef __attribute__((ext_vector_type(8))) short s16x8;

// ---------------- output offsets (f32 elements) ----------------
#define O_FM    0ULL
#define O_TRIP  67108864ULL
#define O_KL    67108865ULL
#define O_DIST  67108866ULL
#define O_AATT  67108867ULL
#define O_NATT  67141635ULL
#define O_ANATT 67174403ULL
#define O_NAATT 67207171ULL

// ---------------- ws offsets (bytes), total ~18.6 MB (ws_size ~1 GB) ----------------
#define WS_ATTB  0ULL          // att bf16 [65536][128]
#define WS_BCT   16777216ULL   // bf16 [512 n][128 k]: k<64 = pam^T, k>=64 = pnm^T
#define WS_PVT   16908288ULL   // bf16 [512 n][64 k] = pnv^T
#define WS_PAM   16973824ULL   // f32 [64][512]
#define WS_PNM   17104896ULL   // f32 [64][512]
#define WS_PNV   17235968ULL   // f32 [64][512]
#define WS_MBH   17367040ULL   // bf16 [128 k][512 d] mem hi
#define WS_MBL   17498112ULL   // bf16 [128 k][512 d] mem lo
#define WS_TATT  17629184ULL   // f32 [3][32768]
#define WS_IDX   18022400ULL   // int [3][64][40]
#define WS_GATH  18053120ULL   // f32 [3][64][512]
#define WS_NORM  18446336ULL   // f32 [128]
#define WS_KL    18446848ULL   // f32
#define WS_TRIPB 18447360ULL   // f32 [64]
#define WS_SUM   18447616ULL   // f32 [64][512]

__device__ __forceinline__ u16 f2bf(float f) {
    union { float f; unsigned int u; } c; c.f = f;
    unsigned int r = c.u + 0x7fffu + ((c.u >> 16) & 1u);
    return (u16)(r >> 16);
}
__device__ __forceinline__ float bf2f(u16 h) {
    union { unsigned int u; float f; } c; c.u = ((unsigned int)h) << 16;
    return c.f;
}

__device__ __forceinline__ float blk_sum(float v, float* red) {
    #pragma unroll
    for (int o = 32; o; o >>= 1) v += __shfl_xor(v, o);
    int tid = threadIdx.x;
    if ((tid & 63) == 0) red[tid >> 6] = v;
    __syncthreads();
    float r = red[0] + red[1] + red[2] + red[3];
    __syncthreads();
    return r;
}

// 512-thread block sum; waves 4-7 padded with zeros -> bit-identical to 4-wave version
__device__ __forceinline__ float blk_sum8(float v, float* red, int tid) {
    #pragma unroll
    for (int o = 32; o; o >>= 1) v += __shfl_xor(v, o);
    if ((tid & 63) == 0) red[tid >> 6] = v;
    __syncthreads();
    float r = red[0];
    #pragma unroll
    for (int i = 1; i < 8; ++i) r += red[i];
    __syncthreads();
    return r;
}

// stage a 128x32 bf16 tile into LDS linearly (512 threads, one 16B load each)
__device__ __forceinline__ void stage32_512(const u16* __restrict__ g, int row0, int ld, int k0,
                                            u16* s, int tid) {
    const u16* src = g + (size_t)(row0 + (tid >> 2)) * ld + k0 + (tid & 3) * 8;
    __builtin_amdgcn_global_load_lds((const __attribute__((address_space(1))) void*)src,
                                     (__attribute__((address_space(3))) void*)(s + tid * 8),
                                     16, 0, 0);
}

// ---------------- k_pp: prep (256 blocks) + proj (192 blocks) ----------------
__global__ __launch_bounds__(256) void k_pp(const float* __restrict__ Amem, const float* __restrict__ Nmem,
                                            const float* __restrict__ Wmu, const float* __restrict__ Wvar,
                                            char* __restrict__ ws) {
    __shared__ float mr[512];
    int bid = blockIdx.x, tid = threadIdx.x;
    if (bid < 256) {
        int i = bid * 256 + tid;
        if (i == 0) *(float*)(ws + WS_KL) = 0.f;
        if (i < 32768) ((float*)(ws + WS_SUM))[i] = 0.f;
        int k = i >> 9, d = i & 511;
        float v = (k < 64) ? Amem[(size_t)k * 512 + d] : Nmem[(size_t)(k - 64) * 512 + d];
        u16 h = f2bf(v);
        ((u16*)(ws + WS_MBH))[i] = h;
        ((u16*)(ws + WS_MBL))[i] = f2bf(v - bf2f(h));
        return;
    }
    int pb = bid - 256;
    float* pam = (float*)(ws + WS_PAM);
    float* pnm = (float*)(ws + WS_PNM);
    float* pnv = (float*)(ws + WS_PNV);
    u16* bct = (u16*)(ws + WS_BCT);
    u16* pvt = (u16*)(ws + WS_PVT);
    int mat = pb >> 6, k = pb & 63;
    const float* mrow = ((mat == 0) ? Amem : Nmem) + (size_t)k * 512;
    const float* W = (mat == 2) ? Wvar : Wmu;
    mr[tid] = mrow[tid]; mr[tid + 256] = mrow[tid + 256];
    __syncthreads();
    float s0 = 0.f, s1 = 0.f;
    for (int d = 0; d < 512; ++d) {
        float m = mr[d];
        s0 += m * W[(size_t)d * 512 + tid];
        s1 += m * W[(size_t)d * 512 + tid + 256];
    }
    if (mat == 0) {
        pam[(size_t)k * 512 + tid] = s0; pam[(size_t)k * 512 + tid + 256] = s1;
        bct[(size_t)tid * 128 + k] = f2bf(s0); bct[(size_t)(tid + 256) * 128 + k] = f2bf(s1);
    } else if (mat == 1) {
        pnm[(size_t)k * 512 + tid] = s0; pnm[(size_t)k * 512 + tid + 256] = s1;
        bct[(size_t)tid * 128 + 64 + k] = f2bf(s0); bct[(size_t)(tid + 256) * 128 + 64 + k] = f2bf(s1);
    } else {
        pnv[(size_t)k * 512 + tid] = s0; pnv[(size_t)k * 512 + tid + 256] = s1;
        pvt[(size_t)tid * 64 + k] = f2bf(s0); pvt[(size_t)(tid + 256) * 64 + k] = f2bf(s1);
    }
}

// ---------------- dots via split-bf16 MFMA (round-13 proven) ----------------
__global__ __launch_bounds__(512) void k_dots(const float* __restrict__ x, char* __restrict__ ws,
                                              float* __restrict__ out) {
    __shared__ u16 sXh[128 * 32];
    __shared__ u16 sXl[128 * 32];
    __shared__ u16 sBh[128 * 32];
    __shared__ u16 sBl[128 * 32];

    int tid = threadIdx.x;
    int row0 = blockIdx.x * 128;
    const u16* mbh = (const u16*)(ws + WS_MBH);
    const u16* mbl = (const u16*)(ws + WS_MBL);
    u16* attb = (u16*)(ws + WS_ATTB);
    int lane = tid & 63, wid = tid >> 6;
    int cl = lane & 15, rq = lane >> 4;

    f32x4 acc[8];
    #pragma unroll
    for (int i = 0; i < 8; ++i) acc[i] = (f32x4)0.f;

    for (int dc = 0; dc < 16; ++dc) {
        int d0 = dc * 32;
        {
            int r = tid >> 2, q4 = tid & 3;
            const float* sp = x + (size_t)(row0 + r) * 512 + d0 + q4 * 8;
            float* op = out + (size_t)(row0 + r) * 1024 + d0 + q4 * 8;
            f32x4 v0 = *(const f32x4*)(sp);
            f32x4 v1 = *(const f32x4*)(sp + 4);
            *(f32x4*)(op) = v0;
            *(f32x4*)(op + 4) = v1;
            s16x8 hs, ls;
            #pragma unroll
            for (int j = 0; j < 4; ++j) {
                u16 h0 = f2bf(v0[j]); hs[j] = (short)h0; ls[j] = (short)f2bf(v0[j] - bf2f(h0));
                u16 h1 = f2bf(v1[j]); hs[4 + j] = (short)h1; ls[4 + j] = (short)f2bf(v1[j] - bf2f(h1));
            }
            *(s16x8*)&sXh[r * 32 + q4 * 8] = hs;
            *(s16x8*)&sXl[r * 32 + q4 * 8] = ls;
        }
        stage32_512(mbh, 0, 512, d0, sBh, tid);
        stage32_512(mbl, 0, 512, d0, sBl, tid);
        __syncthreads();
        s16x8 axh = *(const s16x8*)&sXh[(wid * 16 + cl) * 32 + rq * 8];
        s16x8 axl = *(const s16x8*)&sXl[(wid * 16 + cl) * 32 + rq * 8];
        #pragma unroll
        for (int ni = 0; ni < 8; ++ni) {
            s16x8 bh = *(const s16x8*)&sBh[(ni * 16 + cl) * 32 + rq * 8];
            s16x8 bl = *(const s16x8*)&sBl[(ni * 16 + cl) * 32 + rq * 8];
            acc[ni] = __builtin_amdgcn_mfma_f32_16x16x32_bf16(axh, bh, acc[ni], 0, 0, 0);
            acc[ni] = __builtin_amdgcn_mfma_f32_16x16x32_bf16(axh, bl, acc[ni], 0, 0, 0);
            acc[ni] = __builtin_amdgcn_mfma_f32_16x16x32_bf16(axl, bh, acc[ni], 0, 0, 0);
        }
        __syncthreads();
    }

    #pragma unroll
    for (int ni = 0; ni < 8; ++ni) {
        #pragma unroll
        for (int q = 0; q < 4; ++q) {
            float logit = acc[ni][q] * 0.044194173824159216f;  // 1/sqrt(512)
            float av = 1.f / (1.f + expf(-logit));
            acc[ni][q] = av;
            attb[(size_t)(row0 + wid * 16 + rq * 4 + q) * 128 + ni * 16 + cl] = f2bf(av);
        }
    }

    unsigned long long gmask = 0xFFFFull << (lane & 48);
    float* tatt = (float*)(ws + WS_TATT);
    int half = row0 >> 15;
    #pragma unroll
    for (int q = 0; q < 4; ++q) {
        #pragma unroll
        for (int side = 0; side < 2; ++side) {
            float v0 = acc[side * 4 + 0][q], v1 = acc[side * 4 + 1][q];
            float v2 = acc[side * 4 + 2][q], v3 = acc[side * 4 + 3][q];
            float sum5 = 0.f;
            #pragma unroll
            for (int it = 0; it < 5; ++it) {
                float m = v0; int jm = 0;
                if (v1 > m) { m = v1; jm = 1; }
                if (v2 > m) { m = v2; jm = 2; }
                if (v3 > m) { m = v3; jm = 3; }
                float g = m;
                g = fmaxf(g, __shfl_xor(g, 1));
                g = fmaxf(g, __shfl_xor(g, 2));
                g = fmaxf(g, __shfl_xor(g, 4));
                g = fmaxf(g, __shfl_xor(g, 8));
                sum5 += g;
                unsigned long long bl = __ballot(m == g) & gmask;
                int owner = __ffsll(bl) - 1;
                if (lane == owner) {
                    if (jm == 0) v0 = -INFINITY;
                    else if (jm == 1) v1 = -INFINITY;
                    else if (jm == 2) v2 = -INFINITY;
                    else v3 = -INFINITY;
                }
            }
            if (cl == 0) {
                float tv = sum5 / 5.f;
                int lr = (row0 + wid * 16 + rq * 4 + q) & 32767;
                if (half) {
                    if (side == 0) { out[O_AATT + lr]  = tv; tatt[lr] = tv; }
                    else           { out[O_NAATT + lr] = tv; tatt[2 * 32768 + lr] = tv; }
                } else {
                    if (side == 0) { out[O_ANATT + lr] = tv; }
                    else           { out[O_NATT + lr]  = tv; tatt[32768 + lr] = tv; }
                }
            }
        }
    }
}

// ---------------- k_tg: top-33 rank + immediate gather of x means ----------------
__global__ __launch_bounds__(256) void k_tg(const float* __restrict__ tatt, int* __restrict__ idx,
                                            const float* __restrict__ x, float* __restrict__ gath) {
    __shared__ float vals[512];
    __shared__ int il[40];
    int s = blockIdx.x >> 6, b = blockIdx.x & 63, tid = threadIdx.x;
    const float* src = tatt + (size_t)s * 32768 + b * 512;
    vals[tid] = src[tid]; vals[tid + 256] = src[tid + 256];
    __syncthreads();
    #pragma unroll
    for (int e = 0; e < 2; ++e) {
        int i = tid + e * 256;
        float v = vals[i];
        int rank = 0;
        for (int j = 0; j < 512; j += 4) {
            f32x4 w4 = *(const f32x4*)&vals[j];
            rank += (w4.x > v) || (w4.x == v && (j + 0) < i);
            rank += (w4.y > v) || (w4.y == v && (j + 1) < i);
            rank += (w4.z > v) || (w4.z == v && (j + 2) < i);
            rank += (w4.w > v) || (w4.w == v && (j + 3) < i);
        }
        if (rank < 33) { idx[(s * 64 + b) * 40 + rank] = i; il[rank] = i; }
    }
    __syncthreads();
    int srcb = (s == 1) ? b : 64 + b;
    const float* xb = x + (size_t)srcb * 262144;
    int d0 = tid * 2;
    float a0 = 0.f, a1 = 0.f;
    for (int i = 0; i < 33; ++i) {
        const float* p = xb + (size_t)il[i] * 512 + d0;
        a0 += p[0]; a1 += p[1];
    }
    gath[((size_t)s * 64 + b) * 512 + d0]     = a0 / 33.f;
    gath[((size_t)s * 64 + b) * 512 + d0 + 1] = a1 / 33.f;
}

// ---------------- k_post bodies ----------------
__device__ __forceinline__ void body_G1(char* smem, int m0, int c0, int tid,
                                        const u16* __restrict__ attb, const u16* __restrict__ bct,
                                        const u16* __restrict__ pvt, const float* __restrict__ bmu,
                                        const float* __restrict__ bvar, const float* __restrict__ epsv,
                                        float* __restrict__ fm, float* __restrict__ klacc) {
    u16* sAA = (u16*)(smem);
    u16* sAN = (u16*)(smem + 8192);
    u16* sBA = (u16*)(smem + 16384);
    u16* sBN = (u16*)(smem + 24576);
    u16* sBV = (u16*)(smem + 32768);
    float* red = (float*)(smem + 40960);
    int lane = tid & 63, wid = tid >> 6;
    int wr = wid >> 2, wc = wid & 3;
    int cl = lane & 15, rq = lane >> 4;

    f32x4 aA[4][2], aN[4][2], aV[4][2];
    #pragma unroll
    for (int i = 0; i < 4; ++i)
        #pragma unroll
        for (int j = 0; j < 2; ++j) { aA[i][j] = (f32x4)0.f; aN[i][j] = (f32x4)0.f; aV[i][j] = (f32x4)0.f; }

    for (int kt = 0; kt < 2; ++kt) {
        stage32_512(attb, m0, 128, kt * 32, sAA, tid);
        stage32_512(attb, m0, 128, 64 + kt * 32, sAN, tid);
        stage32_512(bct, c0, 128, kt * 32, sBA, tid);
        stage32_512(bct, c0, 128, 64 + kt * 32, sBN, tid);
        stage32_512(pvt, c0, 64, kt * 32, sBV, tid);
        __syncthreads();
        s16x8 fA[4], fN[4], bA[2], bN[2], bV[2];
        #pragma unroll
        for (int i = 0; i < 4; ++i) {
            fA[i] = *(const s16x8*)&sAA[(wr * 64 + i * 16 + cl) * 32 + rq * 8];
            fN[i] = *(const s16x8*)&sAN[(wr * 64 + i * 16 + cl) * 32 + rq * 8];
        }
        #pragma unroll
        for (int n = 0; n < 2; ++n) {
            bA[n] = *(const s16x8*)&sBA[(wc * 32 + n * 16 + cl) * 32 + rq * 8];
            bN[n] = *(const s16x8*)&sBN[(wc * 32 + n * 16 + cl) * 32 + rq * 8];
            bV[n] = *(const s16x8*)&sBV[(wc * 32 + n * 16 + cl) * 32 + rq * 8];
        }
        #pragma unroll
        for (int mi = 0; mi < 4; ++mi)
            #pragma unroll
            for (int ni = 0; ni < 2; ++ni) {
                aA[mi][ni] = __builtin_amdgcn_mfma_f32_16x16x32_bf16(fA[mi], bA[ni], aA[mi][ni], 0, 0, 0);
                aN[mi][ni] = __builtin_amdgcn_mfma_f32_16x16x32_bf16(fN[mi], bN[ni], aN[mi][ni], 0, 0, 0);
                aV[mi][ni] = __builtin_amdgcn_mfma_f32_16x16x32_bf16(fN[mi], bV[ni], aV[mi][ni], 0, 0, 0);
            }
        __syncthreads();
    }

    float kll = 0.f;
    #pragma unroll
    for (int mi = 0; mi < 4; ++mi)
        #pragma unroll
        for (int ni = 0; ni < 2; ++ni) {
            int col = c0 + wc * 32 + ni * 16 + cl;
            int rowb = m0 + wr * 64 + mi * 16 + rq * 4;
            float bm = bmu[col], bv = bvar[col];
            #pragma unroll
            for (int q = 0; q < 4; ++q) {
                int row = rowb + q;
                float muN = aN[mi][ni][q] + bm;
                float var = aV[mi][ni][q] + bv;
                float ev = expf(var);
                float muA = aA[mi][ni][q] + bm;
                fm[(size_t)row * 1024 + 512 + col] =
                    muN + epsv[(size_t)row * 512 + col] * sqrtf(ev) + muA;
                kll += 1.f + var - muN * muN - ev;
            }
        }
    #pragma unroll
    for (int o = 32; o; o >>= 1) kll += __shfl_xor(kll, o);
    if (lane == 0) red[wid] = kll;
    __syncthreads();
    if (tid == 0) {
        float s = 0.f;
        #pragma unroll
        for (int i = 0; i < 8; ++i) s += red[i];
        atomicAdd(klacc, s);
    }
}

__device__ __forceinline__ void body_G3(char* smem, int m0, int c0, int tid,
                                        const u16* __restrict__ attb, const u16* __restrict__ bct,
                                        const float* __restrict__ bmu, float* __restrict__ fm) {
    u16* sA = (u16*)(smem);
    u16* sB = (u16*)(smem + 8192);
    int lane = tid & 63, wid = tid >> 6;
    int wr = wid >> 2, wc = wid & 3;
    int cl = lane & 15, rq = lane >> 4;

    f32x4 acc[4][2];
    #pragma unroll
    for (int i = 0; i < 4; ++i)
        #pragma unroll
        for (int j = 0; j < 2; ++j) acc[i][j] = (f32x4)0.f;

    for (int kt = 0; kt < 4; ++kt) {
        stage32_512(attb, 32768 + m0, 128, kt * 32, sA, tid);
        stage32_512(bct, c0, 128, kt * 32, sB, tid);
        __syncthreads();
        s16x8 fa[4], fb[2];
        #pragma unroll
        for (int i = 0; i < 4; ++i)
            fa[i] = *(const s16x8*)&sA[(wr * 64 + i * 16 + cl) * 32 + rq * 8];
        #pragma unroll
        for (int n = 0; n < 2; ++n)
            fb[n] = *(const s16x8*)&sB[(wc * 32 + n * 16 + cl) * 32 + rq * 8];
        #pragma unroll
        for (int mi = 0; mi < 4; ++mi)
            #pragma unroll
            for (int ni = 0; ni < 2; ++ni)
                acc[mi][ni] = __builtin_amdgcn_mfma_f32_16x16x32_bf16(fa[mi], fb[ni], acc[mi][ni], 0, 0, 0);
        __syncthreads();
    }
    #pragma unroll
    for (int mi = 0; mi < 4; ++mi)
        #pragma unroll
        for (int ni = 0; ni < 2; ++ni) {
            int col = c0 + wc * 32 + ni * 16 + cl;
            int rowb = 32768 + m0 + wr * 64 + mi * 16 + rq * 4;
            float bm2 = 2.f * bmu[col];
            #pragma unroll
            for (int q = 0; q < 4; ++q)
                fm[(size_t)(rowb + q) * 1024 + 512 + col] = acc[mi][ni][q] + bm2;
        }
}

__device__ __forceinline__ void body_g2a(char* smem, int blk, int tid,
                                         const int* __restrict__ idx, const u16* __restrict__ attb,
                                         const float* __restrict__ pnm, const float* __restrict__ pnv,
                                         const float* __restrict__ bmu, const float* __restrict__ bvar,
                                         const float* __restrict__ epsv, float* __restrict__ SUM) {
    float* arow = (float*)smem;
    int b = blk / 3, seg = blk % 3;
    float s0 = 0.f, s1 = 0.f;
    for (int i = seg * 11; i < seg * 11 + 11; ++i) {
        int t = idx[(64 + b) * 40 + i];   // N_idx
        size_t r = (size_t)b * 512 + t;
        __syncthreads();
        if (tid < 64) arow[tid] = bf2f(attb[r * 128 + 64 + tid]);
        __syncthreads();
        if (tid < 256) {
            float mu0 = bmu[tid], mu1 = bmu[tid + 256];
            float v0 = bvar[tid], v1 = bvar[tid + 256];
            for (int k = 0; k < 64; ++k) {
                float a = arow[k];
                mu0 += a * pnm[(size_t)k * 512 + tid];
                mu1 += a * pnm[(size_t)k * 512 + tid + 256];
                v0  += a * pnv[(size_t)k * 512 + tid];
                v1  += a * pnv[(size_t)k * 512 + tid + 256];
            }
            s0 += mu0 + epsv[r * 512 + tid]       * sqrtf(expf(v0));
            s1 += mu1 + epsv[r * 512 + tid + 256] * sqrtf(expf(v1));
        }
    }
    if (tid < 256) {
        atomicAdd(&SUM[(size_t)b * 512 + tid], s0);
        atomicAdd(&SUM[(size_t)b * 512 + tid + 256], s1);
    }
}

__device__ __forceinline__ void body_g2b(char* smem, int b, int tid,
                                         const int* __restrict__ idx, const u16* __restrict__ attb,
                                         const float* __restrict__ pam, const float* __restrict__ bmu,
                                         float* __restrict__ norms) {
    float* meanA = (float*)smem;
    float* red = (float*)(smem + 256);
    if (tid < 64) {
        float s = 0.f;
        for (int i = 0; i < 33; ++i) {
            int t = idx[b * 40 + i];      // A_idx
            s += bf2f(attb[(size_t)(32768 + b * 512 + t) * 128 + tid]);
        }
        meanA[tid] = s * (1.f / 33.f);
    }
    __syncthreads();
    float ssv = 0.f;
    if (tid < 256) {
        float s0 = bmu[tid], s1 = bmu[tid + 256];
        #pragma unroll 4
        for (int k = 0; k < 64; ++k) {
            float m = meanA[k];
            s0 += m * pam[(size_t)k * 512 + tid];
            s1 += m * pam[(size_t)k * 512 + tid + 256];
        }
        ssv = s0 * s0 + s1 * s1;
    }
    float ss = blk_sum8(ssv, red, tid);
    if (tid == 0) norms[64 + b] = sqrtf(ss);
}

// ---------------- k_post: kG1 (1024) + kG3 (1024) + g2a (192) + g2b (64) ----------------
__global__ __launch_bounds__(512) void k_post(const u16* __restrict__ attb, const u16* __restrict__ bct,
                                              const u16* __restrict__ pvt, const float* __restrict__ bmu,
                                              const float* __restrict__ bvar, const float* __restrict__ epsv,
                                              const int* __restrict__ idx, const float* __restrict__ pam,
                                              const float* __restrict__ pnm, const float* __restrict__ pnv,
                                              float* __restrict__ fm, float* __restrict__ klacc,
                                              float* __restrict__ SUM, float* __restrict__ norms) {
    __shared__ __align__(16) char smem[41024];
    int bid = blockIdx.x, tid = threadIdx.x;
    if (bid < 1024) {
        body_G1(smem, (bid >> 2) * 128, (bid & 3) * 128, tid, attb, bct, pvt, bmu, bvar, epsv, fm, klacc);
    } else if (bid < 2048) {
        int b2 = bid - 1024;
        body_G3(smem, (b2 >> 2) * 128, (b2 & 3) * 128, tid, attb, bct, bmu, fm);
    } else if (bid < 2240) {
        body_g2a(smem, bid - 2048, tid, idx, attb, pnm, pnv, bmu, bvar, epsv, SUM);
    } else {
        body_g2b(smem, bid - 2240, tid, idx, attb, pam, bmu, norms);
    }
}

// ---------------- k_nt: norm2a (64) + triplet (64) ----------------
__global__ __launch_bounds__(256) void k_nt(const float* __restrict__ SUM, const float* __restrict__ gath,
                                            float* __restrict__ norms, float* __restrict__ tripb) {
    __shared__ float red[8];
    int bid = blockIdx.x, tid = threadIdx.x;
    if (bid < 64) {
        int b = bid;
        float s0 = SUM[(size_t)b * 512 + tid] / 33.f;
        float s1 = SUM[(size_t)b * 512 + tid + 256] / 33.f;
        float ss = blk_sum(s0 * s0 + s1 * s1, red);
        if (tid == 0) norms[b] = sqrtf(ss);
    } else {
        int b = bid - 64;
        const float* a = gath + (size_t)(64 + b) * 512;
        const float* p = gath + (size_t)(128 + b) * 512;
        const float* n = gath + (size_t)(b) * 512;
        float a0 = a[tid], a1 = a[tid + 256];
        float p0 = p[tid], p1 = p[tid + 256];
        float n0 = n[tid], n1 = n[tid + 256];
        float na  = sqrtf(blk_sum(a0 * a0 + a1 * a1, red));
        float npv = sqrtf(blk_sum(p0 * p0 + p1 * p1, red));
        float nn  = sqrtf(blk_sum(n0 * n0 + n1 * n1, red));
        float e0 = a0 / na - p0 / npv + 1e-6f, e1 = a1 / na - p1 / npv + 1e-6f;
        float f0 = a0 / na - n0 / nn  + 1e-6f, f1 = a1 / na - n1 / nn  + 1e-6f;
        float dap = sqrtf(blk_sum(e0 * e0 + e1 * e1, red));
        float dan = sqrtf(blk_sum(f0 * f0 + f1 * f1, red));
        if (tid == 0) tripb[b] = fmaxf(dap - dan + 1.f, 0.f);
    }
}

// ---------------- finalize: triplet + distance + kl ----------------
__global__ __launch_bounds__(64) void k_final(const float* __restrict__ norms, const float* __restrict__ klacc,
                                              const float* __restrict__ tripb, float* __restrict__ out) {
    int tid = threadIdx.x;
    float v = fmaxf(100.f - norms[64 + tid] + norms[tid], 0.f);
    float t = tripb[tid];
    #pragma unroll
    for (int o = 32; o; o >>= 1) { v += __shfl_xor(v, o); t += __shfl_xor(t, o); }
    if (tid == 0) {
        out[O_DIST] = v / 64.f;
        out[O_TRIP] = t / 64.f;
        out[O_KL]   = -0.5f * (*klacc) / 32768.f;
    }
}

extern "C" void kernel_launch(void* const* d_in, const int* in_sizes, int n_in,
                              void* d_out, int out_size, void* d_ws, size_t ws_size,
                              hipStream_t stream) {
    const float* x    = (const float*)d_in[0];
    const float* Amem = (const float*)d_in[1];
    const float* Nmem = (const float*)d_in[2];
    const float* Wmu  = (const float*)d_in[3];
    const float* bmu  = (const float*)d_in[4];
    const float* Wvar = (const float*)d_in[5];
    const float* bvar = (const float*)d_in[6];
    const float* eps  = (const float*)d_in[7];
    float* out = (float*)d_out;
    char* ws = (char*)d_ws;
    const u16* attb  = (const u16*)(ws + WS_ATTB);
    const u16* bct   = (const u16*)(ws + WS_BCT);
    const u16* pvt   = (const u16*)(ws + WS_PVT);
    const float* pam = (const float*)(ws + WS_PAM);
    const float* pnm = (const float*)(ws + WS_PNM);
    const float* pnv = (const float*)(ws + WS_PNV);
    const int* idx   = (const int*)(ws + WS_IDX);

    k_pp<<<448, 256, 0, stream>>>(Amem, Nmem, Wmu, Wvar, ws);
    k_dots<<<512, 512, 0, stream>>>(x, ws, out);
    k_tg<<<192, 256, 0, stream>>>((const float*)(ws + WS_TATT), (int*)(ws + WS_IDX), x,
                                  (float*)(ws + WS_GATH));
    k_post<<<2304, 512, 0, stream>>>(attb, bct, pvt, bmu, bvar, eps, idx, pam, pnm, pnv,
                                     out, (float*)(ws + WS_KL), (float*)(ws + WS_SUM),
                                     (float*)(ws + WS_NORM));
    k_nt<<<128, 256, 0, stream>>>((const float*)(ws + WS_SUM), (const float*)(ws + WS_GATH),
                                  (float*)(ws + WS_NORM), (float*)(ws + WS_TRIPB));
    k_final<<<1, 64, 0, stream>>>((const float*)(ws + WS_NORM), (const float*)(ws + WS_KL),
                                  (const float*)(ws + WS_TRIPB), out);
}